// Round 15
// baseline (438.424 us; speedup 1.0000x reference)
//
#include <hip/hip_runtime.h>
#include <cstdint>

#define VOCAB 100000
#define EMB 300
#define NE 301         // 300 emb dims + 1 bias row (evoke_b)
#define KP 128         // padded h (bf16 elements per p-row)
#define EKSTRIDE 28672 // bytes per e slab = 7 tiles * 4 ks * 1024 B
#define NP 128         // G row stride (floats)
#define BM 64
#define BTOT 16384
#define PSZ 112        // stored p per row in mv partials
#define NGRP 4
#define FSB 16         // samples per k_fin block
#define NPREP (NE + BTOT / 16 + 128)   // 1453 fused-prep blocks

typedef __attribute__((ext_vector_type(8))) short short8;
typedef __attribute__((ext_vector_type(4))) float f32x4;

__device__ __forceinline__ unsigned short f2bf(float f) {
    uint32_t u = __float_as_uint(f);
    uint32_t r = (u + 0x7fffu + ((u >> 16) & 1u)) >> 16;   // RNE
    return (unsigned short)r;
}

// ---------------------------------------------------------------------------
// Fused prep: blocks [0,301) pack evoke_k -> ekp (frag-ordered bf16);
// blocks [301,1325) run the time MLP -> tvp; blocks [1325,1453) build
// G = last_k last_k^T, vvec, c0, and zero out.
// ---------------------------------------------------------------------------
__global__ __launch_bounds__(256) void k_prep(
    const float* __restrict__ evoke_k, const float* __restrict__ evoke_b,
    unsigned short* __restrict__ ekp,
    const float* __restrict__ times,
    const float* __restrict__ h1_k, const float* __restrict__ h1_b,
    const float* __restrict__ h2_k, const float* __restrict__ h2_b,
    unsigned short* __restrict__ tvp,
    const float* __restrict__ last_k, const float* __restrict__ last_b,
    float* __restrict__ G, float* __restrict__ vvec,
    float* __restrict__ c0, float* __restrict__ out) {
    __shared__ float h1s[16][100];
    __shared__ float row[EMB];
    const int b = blockIdx.x;

    if (b < NE) {
        // ---- ekprep: frag-ordered pack.  byte off = e*EKSTRIDE +
        // ((t*4+ks)*64+lane)*16 holding ek[p=t*16+(lane&15)][h=ks*32+(lane>>4)*8..+7]
        int e = b;
        const float* src = (e < EMB) ? (evoke_k + (size_t)e * 10000) : evoke_b;
        uint32_t* dst = (uint32_t*)(ekp + (size_t)e * (EKSTRIDE / 2));
#pragma unroll
        for (int it = 0; it < 7; ++it) {
            int c    = it * 256 + threadIdx.x;   // 0..1791
            int lane = c & 63;
            int ks   = (c >> 6) & 3;
            int t    = c >> 8;                   // 0..6
            int p    = t * 16 + (lane & 15);
            int h0   = ks * 32 + (lane >> 4) * 8;
            uint32_t ov[4] = {0u, 0u, 0u, 0u};
            if (p < 100) {
#pragma unroll
                for (int j = 0; j < 8; ++j) {
                    int h = h0 + j;
                    float f = (h < 100) ? src[p * 100 + h] : 0.f;
                    ov[j >> 1] |= (uint32_t)f2bf(f) << ((j & 1) * 16);
                }
            }
            uint32_t* o = dst + (size_t)c * 4;
            o[0] = ov[0]; o[1] = ov[1]; o[2] = ov[2]; o[3] = ov[3];
        }
    } else if (b < NE + BTOT / 16) {
        // ---- time MLP -> tv bf16 [B][128]
        int b0 = (b - NE) * 16;
        for (int idx = threadIdx.x; idx < 1600; idx += 256) {
            int bb = idx / 100, i = idx - bb * 100;
            h1s[bb][i] = tanhf(times[b0 + bb] * h1_k[i] + h1_b[i]);
        }
        __syncthreads();
        for (int idx = threadIdx.x; idx < 1600; idx += 256) {
            int bb = idx / 100, j = idx - bb * 100;
            float acc = h2_b[j];
            for (int i = 0; i < 100; ++i) acc += h1s[bb][i] * h2_k[i * 100 + j];
            tvp[(size_t)(b0 + bb) * KP + j] = f2bf(tanhf(acc));
        }
        for (int idx = threadIdx.x; idx < 16 * 28; idx += 256) {
            int bb = idx / 28, j = 100 + (idx - bb * 28);
            tvp[(size_t)(b0 + bb) * KP + j] = 0;
        }
    } else {
        // ---- gprep: G, vvec, c0, out=0
        int p = b - NE - BTOT / 16;   // 0..127
        int q = threadIdx.x;          // active q<128
        for (int d = threadIdx.x; d < EMB; d += 256)
            row[d] = (p < 100) ? last_k[p * EMB + d] : 0.f;
        __syncthreads();
        if (q < 128) {
            float acc = 0.f;
            if (p < 100 && q < 100) {
                for (int d = 0; d < EMB; ++d) acc += row[d] * last_k[q * EMB + d];
            }
            G[p * NP + q] = acc;
            if (q == 0) {
                float a = 0.f;
                if (p < 100) {
                    for (int d = 0; d < EMB; ++d) a += row[d] * last_b[d];
                }
                vvec[p] = a;
                if (p == 0) {
                    float s = 0.f;
                    for (int d = 0; d < EMB; ++d) s += last_b[d] * last_b[d];
                    *c0 = s;
                    *out = 0.f;
                }
            }
        }
    }
}

// ---------------------------------------------------------------------------
// Main: 64 batch rows x 112 p x QUARTER e-range per block.  1024 blocks, 256
// threads, 2 blocks/CU.  e-groups XCD-PINNED via g=(blockIdx&7)>>1 -> L2-
// resident ekp slice (r10: FETCH 56 MB).  Inline-asm global_load_dwordx4 +
// counted vmcnt(8), 2-deep.  f32 embl (r12: no unpack VALU).
// OCCUPANCY IS STRUCTURALLY 2 waves/SIMD: true per-wave regs = 124 arch +
// ~64 unified-file accumulator ~= 190.  r14 tried (256,3) (cap ~170): the
// allocator SPILLED, and scratch spills are VMEM ops that increment vmcnt,
// corrupting the counted vmcnt(8) schedule -> NaN.  Counted-vmcnt pipelines
// and register spilling are mutually exclusive -- do not raise the occupancy
// target on this kernel.  (r13 e-rotation: neutral, reverted.)
// ---------------------------------------------------------------------------
__global__ __launch_bounds__(256, 2) void k_main(
    const int* __restrict__ targets, const int* __restrict__ contexts,
    const float* __restrict__ targetemb, const float* __restrict__ contextemb,
    const unsigned short* __restrict__ ekp, const unsigned short* __restrict__ tvp,
    float* __restrict__ mvpt, float* __restrict__ mvpc) {
    extern __shared__ char smem[];
    // embl f32 [76 e_local][2 br * 64 b] = 38,912 B

    const int tid  = threadIdx.x;
    const int lane = tid & 63;
    const int w    = tid >> 6;       // wave 0..3
    const int l15  = lane & 15;
    const int l4   = lane >> 4;      // 0..3
    const int low3 = blockIdx.x & 7;
    const int g    = low3 >> 1;                              // e-group 0..3 (XCD-pinned)
    const int bt   = ((blockIdx.x >> 3) << 1) | (low3 & 1);  // batch tile 0..255
    const int m0   = bt * BM;
    const int e0   = (g == 0) ? 0 : (1 + 75 * g);            // 0,76,151,226
    const int ecnt = (g == 0) ? 76 : 75;
    const int nreal= (g == 3) ? 74 : ecnt;                   // g3 local 74 = bias row

    float* embl = (float*)smem;

    // ---- stationary tv A-frags (bf16): m = l15, k-chunk = ks*32 + l4*8 ----
    short8 afrag[4][4];
#pragma unroll
    for (int mt = 0; mt < 4; ++mt) {
        int bg = m0 + mt * 16 + l15;
#pragma unroll
        for (int ks = 0; ks < 4; ++ks) {
            afrag[mt][ks] = *(const short8*)(tvp + (size_t)bg * KP + ks * 32 + l4 * 8);
        }
    }

    // ---- per-wave B-frag activity + per-lane voffsets (ks folded into imm) ----
    bool act[2];
    int  voff[2];
#pragma unroll
    for (int nt = 0; nt < 2; ++nt) {
        int t = w * 2 + nt;          // n-tile 0..7; tile 7 doesn't exist (p<112)
        act[nt] = (t < 7);
        // dummy slot (wave 3, nt=1): uniform voffset 0 -> one 64B line via TA
        voff[nt] = (t < 7) ? (t * 4096 + lane * 16) : 0;
    }

    // ---- pinned async loads: 8 x global_load_dwordx4 per e-slab ----
    auto issue = [&](short8 (&buf)[2][4], int el) {
        int eg = e0 + ((el < ecnt) ? el : (ecnt - 1));
        uint64_t base = (uint64_t)(const void*)ekp + (uint64_t)eg * EKSTRIDE;
#pragma unroll
        for (int nt = 0; nt < 2; ++nt) {
            asm volatile("global_load_dwordx4 %0, %1, %2 offset:0"
                         : "=v"(buf[nt][0]) : "v"(voff[nt]), "s"(base));
            asm volatile("global_load_dwordx4 %0, %1, %2 offset:1024"
                         : "=v"(buf[nt][1]) : "v"(voff[nt]), "s"(base));
            asm volatile("global_load_dwordx4 %0, %1, %2 offset:2048"
                         : "=v"(buf[nt][2]) : "v"(voff[nt]), "s"(base));
            asm volatile("global_load_dwordx4 %0, %1, %2 offset:3072"
                         : "=v"(buf[nt][3]) : "v"(voff[nt]), "s"(base));
        }
    };
#define WAIT8 do { asm volatile("s_waitcnt vmcnt(8)"); \
                   __builtin_amdgcn_sched_barrier(0x387); } while (0)
#define WAIT0 do { asm volatile("s_waitcnt vmcnt(0)"); \
                   __builtin_amdgcn_sched_barrier(0x387); } while (0)

    // ---- issue first two slabs before the staging barrier ----
    short8 bufA[2][4], bufB[2][4];
    issue(bufA, 0);
    issue(bufB, 1);

    // ---- stage this group's emb scalars (f32): [ecnt e][2 br * 64 b] ----
    {
        int off    = tid & 127;                   // branch*64 + b
        int b      = off & 63;
        int branch = off >> 6;
        int seg    = tid >> 7;                    // 0..1
        int s0 = seg * 38;
        int s1 = (seg == 0) ? 38 : nreal;
        const int* idxp   = branch ? contexts : targets;
        const float* base = branch ? contextemb : targetemb;
        const float* row  = base + (size_t)idxp[m0 + b] * EMB + e0;
        int e = s0;
        for (; e + 3 < s1; e += 4) {
            float4 v = *(const float4*)(row + e);
            embl[(e + 0) * 128 + off] = v.x;
            embl[(e + 1) * 128 + off] = v.y;
            embl[(e + 2) * 128 + off] = v.z;
            embl[(e + 3) * 128 + off] = v.w;
        }
        for (; e < s1; ++e) embl[e * 128 + off] = row[e];
        if (g == 3 && seg == 1) embl[74 * 128 + off] = 1.0f;   // bias e=300 -> 1.0
    }

    f32x4 acc_t[4][2], acc_c[4][2];
    const f32x4 zf = {0.f, 0.f, 0.f, 0.f};
#pragma unroll
    for (int mt = 0; mt < 4; ++mt) {
#pragma unroll
        for (int nt = 0; nt < 2; ++nt) { acc_t[mt][nt] = zf; acc_c[mt][nt] = zf; }
    }

    auto compute = [&](int el, short8 (&buf)[2][4]) {
        f32x4 et[4], ec[4];
#pragma unroll
        for (int mt = 0; mt < 4; ++mt) {
            int row0 = mt * 16 + l4 * 4;
            et[mt] = *(const f32x4*)(embl + el * 128 + row0);        // ds_read_b128
            ec[mt] = *(const f32x4*)(embl + el * 128 + 64 + row0);   // ds_read_b128
        }
#pragma unroll
        for (int nt = 0; nt < 2; ++nt) {
            if (act[nt]) {
                f32x4 S[4];
#pragma unroll
                for (int mt = 0; mt < 4; ++mt) S[mt] = zf;
#pragma unroll
                for (int ks = 0; ks < 4; ++ks) {
#pragma unroll
                    for (int mt = 0; mt < 4; ++mt) {
                        S[mt] = __builtin_amdgcn_mfma_f32_16x16x32_bf16(
                            afrag[mt][ks], buf[nt][ks], S[mt], 0, 0, 0);
                    }
                }
#pragma unroll
                for (int mt = 0; mt < 4; ++mt) {
#pragma unroll
                    for (int r = 0; r < 4; ++r) {
                        acc_t[mt][nt][r] += et[mt][r] * S[mt][r];
                        acc_c[mt][nt][r] += ec[mt][r] * S[mt][r];
                    }
                }
            }
        }
    };

    __syncthreads();   // embl staged; the only barrier in the kernel

    // ---- 2-deep asm-pinned e-loop over this group's slice ----
    const int ITER = (ecnt - 2) >> 1;    // 76->37, 75->36
#pragma unroll 1
    for (int i = 0; i < ITER; ++i) {
        int e = 2 * i;
        WAIT8;
        compute(e, bufA);
        issue(bufA, e + 2);
        WAIT8;
        compute(e + 1, bufB);
        issue(bufB, e + 3);
    }
    {
        int e2 = 2 * ITER;
        WAIT0;
        compute(e2, bufA);
        compute(e2 + 1, bufB);
        if (ecnt & 1) {                  // one leftover (odd groups)
            issue(bufA, e2 + 2);
            WAIT0;
            compute(e2 + 2, bufA);
        }
    }

    // ---- store f32 partials for this group ----
    float* ot = mvpt + (size_t)g * BTOT * PSZ;
    float* oc = mvpc + (size_t)g * BTOT * PSZ;
#pragma unroll
    for (int mt = 0; mt < 4; ++mt) {
#pragma unroll
        for (int nt = 0; nt < 2; ++nt) {
            if (act[nt]) {
                int col = (w * 2 + nt) * 16 + l15;   // 0..111
#pragma unroll
                for (int r = 0; r < 4; ++r) {
                    size_t row = m0 + mt * 16 + l4 * 4 + r;
                    ot[row * PSZ + col] = acc_t[mt][nt][r];
                    oc[row * PSZ + col] = acc_c[mt][nt][r];
                }
            }
        }
    }
}

// ---------------------------------------------------------------------------
// Final v2: 1024 blocks x 256 threads, 16 samples/block, 16 threads/sample.
// G staged in LDS (stride 116 -> <=2-way bank aliasing), partial sums staged
// coalesced, per-thread 7 p-rows x 28 float4 dots from LDS.
// ---------------------------------------------------------------------------
__global__ __launch_bounds__(256, 2) void k_fin(
    const float* __restrict__ labels,
    const float* __restrict__ G, const float* __restrict__ vvec,
    const float* __restrict__ c0p,
    const float* __restrict__ mvpt, const float* __restrict__ mvpc,
    float* __restrict__ out) {
    extern __shared__ float fs[];
    float* Gs   = fs;                    // [112][116]
    float* mts  = fs + 112 * 116;        // [16][112]
    float* mcs  = mts + FSB * PSZ;       // [16][112]
    float* vs   = mcs + FSB * PSZ;       // [112]
    float* lred = vs + PSZ;              // [16]
    const int tid = threadIdx.x;
    const int m0  = blockIdx.x * FSB;

    for (int idx = tid; idx < 112 * 28; idx += 256) {
        int p = idx / 28, qq = idx - p * 28;
        *(float4*)(Gs + p * 116 + qq * 4) = *(const float4*)(G + p * NP + qq * 4);
    }
    for (int idx = tid; idx < FSB * 28; idx += 256) {
        int s = idx / 28, qq = idx - s * 28;
        size_t base = (size_t)(m0 + s) * PSZ + qq * 4;
        float4 st = make_float4(0.f, 0.f, 0.f, 0.f);
        float4 sc = make_float4(0.f, 0.f, 0.f, 0.f);
#pragma unroll
        for (int gg = 0; gg < NGRP; ++gg) {
            float4 a = *(const float4*)(mvpt + (size_t)gg * BTOT * PSZ + base);
            float4 c = *(const float4*)(mvpc + (size_t)gg * BTOT * PSZ + base);
            st.x += a.x; st.y += a.y; st.z += a.z; st.w += a.w;
            sc.x += c.x; sc.y += c.y; sc.z += c.z; sc.w += c.w;
        }
        *(float4*)(mts + s * PSZ + qq * 4) = st;
        *(float4*)(mcs + s * PSZ + qq * 4) = sc;
    }
    if (tid < PSZ) vs[tid] = vvec[tid];
    __syncthreads();

    const int s = tid >> 4;      // 0..15
    const int l = tid & 15;      // 0..15
    float part = 0.f;
#pragma unroll 1
    for (int k = 0; k < 7; ++k) {
        int p = l * 7 + k;       // 0..111 (p>=100 terms are all zero)
        const float4* Gr = (const float4*)(Gs + p * 116);
        const float4* Mr = (const float4*)(mcs + s * PSZ);
        float wq = 0.f;
#pragma unroll
        for (int qq = 0; qq < 28; ++qq) {
            float4 g = Gr[qq];
            float4 m = Mr[qq];
            wq += g.x * m.x + g.y * m.y + g.z * m.z + g.w * m.w;
        }
        float mtv = mts[s * PSZ + p];
        float mcv = mcs[s * PSZ + p];
        part += mtv * wq + vs[p] * (mtv + mcv);
    }
    part += __shfl_xor(part, 1);
    part += __shfl_xor(part, 2);
    part += __shfl_xor(part, 4);
    part += __shfl_xor(part, 8);
    if (l == 0) {
        float logit = part + *c0p;
        float lab = labels[m0 + s];
        lred[s] = fmaxf(logit, 0.f) - logit * lab + log1pf(expf(-fabsf(logit)));
    }
    __syncthreads();
    if (tid == 0) {
        float sum = 0.f;
#pragma unroll
        for (int i = 0; i < FSB; ++i) sum += lred[i];
        atomicAdd(out, sum * (1.0f / 16384.0f));
    }
}

// ---------------------------------------------------------------------------
extern "C" void kernel_launch(void* const* d_in, const int* in_sizes, int n_in,
                              void* d_out, int out_size, void* d_ws, size_t ws_size,
                              hipStream_t stream) {
    const int*   targets    = (const int*)d_in[0];
    const int*   contexts   = (const int*)d_in[1];
    const float* times      = (const float*)d_in[2];
    const float* labels     = (const float*)d_in[3];
    const float* targetemb  = (const float*)d_in[4];
    const float* contextemb = (const float*)d_in[5];
    const float* h1_k       = (const float*)d_in[6];
    const float* h1_b       = (const float*)d_in[7];
    const float* h2_k       = (const float*)d_in[8];
    const float* h2_b       = (const float*)d_in[9];
    const float* evoke_k    = (const float*)d_in[10];
    const float* evoke_b    = (const float*)d_in[11];
    const float* last_k     = (const float*)d_in[12];
    const float* last_b     = (const float*)d_in[13];
    float* out = (float*)d_out;

    char* ws = (char*)d_ws;
    unsigned short* ekp = (unsigned short*)ws;                 // 8,630,272
    unsigned short* tvp = (unsigned short*)(ws + 8630272);     // 4,194,304
    float* G    = (float*)(ws + 8630272 + 4194304);            // 65,536
    float* vv   = (float*)(ws + 8630272 + 4194304 + 65536);    // 512
    float* c0   = (float*)(ws + 8630272 + 4194304 + 65536 + 512);  // 512
    float* mvpt = (float*)(ws + 8630272 + 4194304 + 65536 + 1024); // 29,360,128
    float* mvpc = mvpt + (size_t)NGRP * BTOT * PSZ;                // 29,360,128
    // total ws used: ~71.6 MB

    k_prep<<<dim3(NPREP), dim3(256), 0, stream>>>(
        evoke_k, evoke_b, ekp, times, h1_k, h1_b, h2_k, h2_b, tvp,
        last_k, last_b, G, vv, c0, out);
    k_main<<<dim3(NGRP * BTOT / BM), dim3(256), 38912, stream>>>(
        targets, contexts, targetemb, contextemb, ekp, tvp, mvpt, mvpc);
    k_fin<<<dim3(BTOT / FSB), dim3(256), 66816, stream>>>(
        labels, G, vv, c0, mvpt, mvpc, out);
}